// Round 1
// baseline (5760.438 us; speedup 1.0000x reference)
//
#include <hip/hip_runtime.h>
#include <stdint.h>

constexpr int NN = 100000;   // nodes
constexpr int NE = 1600000;  // edges
constexpr int D  = 64;       // feature dim
constexpr int DO = 128;      // output dim

// ---------------------------------------------------------------------------
// Detect whether edge_index buffer is int64 or int32.
// int64 values are < 2^17, so every odd 32-bit word is 0.
// Random int32 indices in [0,100000) make that astronomically unlikely.
__global__ void detect_i64(const uint32_t* __restrict__ e, int* __restrict__ flag) {
    __shared__ uint32_t acc;
    if (threadIdx.x == 0) acc = 0u;
    __syncthreads();
    uint32_t w = e[2 * threadIdx.x + 1];   // first 256 odd words
    atomicOr(&acc, w);
    __syncthreads();
    if (threadIdx.x == 0) *flag = (acc == 0u) ? 1 : 0;
}

__global__ void convert_edges(const void* __restrict__ e, const int* __restrict__ flag,
                              int* __restrict__ src, int* __restrict__ dst) {
    const int f = *flag;
    const int total = 2 * NE;
    for (int i = blockIdx.x * blockDim.x + threadIdx.x; i < total;
         i += gridDim.x * blockDim.x) {
        int v;
        if (f) v = (int)((const long long*)e)[i];
        else   v = ((const int*)e)[i];
        if (i < NE) src[i] = v;
        else        dst[i - NE] = v;
    }
}

// ---------------------------------------------------------------------------
__global__ void zero_f4(float4* __restrict__ p, int n4) {
    const float4 z = make_float4(0.f, 0.f, 0.f, 0.f);
    for (int i = blockIdx.x * blockDim.x + threadIdx.x; i < n4;
         i += gridDim.x * blockDim.x)
        p[i] = z;
}

__global__ void deg_kernel(const int* __restrict__ dst, float* __restrict__ deg) {
    for (int e = blockIdx.x * blockDim.x + threadIdx.x; e < NE;
         e += gridDim.x * blockDim.x)
        atomicAdd(&deg[dst[e]], 1.0f);
}

__global__ void dinv_kernel(float* __restrict__ deg) {
    int i = blockIdx.x * blockDim.x + threadIdx.x;
    if (i < NN) deg[i] = 1.0f / fmaxf(deg[i], 1.0f);
}

// ---------------------------------------------------------------------------
// agg[dst] += h[src] : 16 threads per edge, float4 gather + 4 f32 atomics.
__global__ void scatter(const float4* __restrict__ h4, const int* __restrict__ src,
                        const int* __restrict__ dst, float* __restrict__ agg) {
    const int total = NE * 16;
    for (int t = blockIdx.x * blockDim.x + threadIdx.x; t < total;
         t += gridDim.x * blockDim.x) {
        const int e = t >> 4;
        const int q = t & 15;
        const float4 v = h4[src[e] * 16 + q];
        float* a = agg + (size_t)dst[e] * 64 + q * 4;
        atomicAdd(a + 0, v.x);
        atomicAdd(a + 1, v.y);
        atomicAdd(a + 2, v.z);
        atomicAdd(a + 3, v.w);
    }
}

// h_new = relu(0.5*(x + agg*dinv)) ; written in place into agg
__global__ void combine0(const float4* __restrict__ x4, float4* __restrict__ agg4,
                         const float* __restrict__ dinv) {
    const int n4 = NN * 16;
    for (int i = blockIdx.x * blockDim.x + threadIdx.x; i < n4;
         i += gridDim.x * blockDim.x) {
        const float di = dinv[i >> 4];
        float4 a = agg4[i];
        float4 x = x4[i];
        float4 r;
        r.x = fmaxf(0.5f * (x.x + a.x * di), 0.f);
        r.y = fmaxf(0.5f * (x.y + a.y * di), 0.f);
        r.z = fmaxf(0.5f * (x.z + a.z * di), 0.f);
        r.w = fmaxf(0.5f * (x.w + a.w * di), 0.f);
        agg4[i] = r;
    }
}

// h_new = h + relu(0.5*(h + agg*dinv)) ; written in place into agg
__global__ void combineR(const float4* __restrict__ h4, float4* __restrict__ agg4,
                         const float* __restrict__ dinv) {
    const int n4 = NN * 16;
    for (int i = blockIdx.x * blockDim.x + threadIdx.x; i < n4;
         i += gridDim.x * blockDim.x) {
        const float di = dinv[i >> 4];
        float4 a = agg4[i];
        float4 h = h4[i];
        float4 r;
        r.x = h.x + fmaxf(0.5f * (h.x + a.x * di), 0.f);
        r.y = h.y + fmaxf(0.5f * (h.y + a.y * di), 0.f);
        r.z = h.z + fmaxf(0.5f * (h.z + a.z * di), 0.f);
        r.w = h.w + fmaxf(0.5f * (h.w + a.w * di), 0.f);
        agg4[i] = r;
    }
}

// ---------------------------------------------------------------------------
// out[i][j] = dot(h[i,:], W[:,j]) + b[j].  W staged in LDS, 2 rows/block.
__global__ __launch_bounds__(256) void matmul_kernel(
    const float* __restrict__ h, const float* __restrict__ W,
    const float* __restrict__ b, float* __restrict__ out) {
    __shared__ float Ws[D * DO];  // 32 KB
    for (int i = threadIdx.x; i < D * DO; i += 256) Ws[i] = W[i];
    __syncthreads();
    const int j   = threadIdx.x & (DO - 1);
    const int r   = threadIdx.x >> 7;  // 0..1
    const int row = blockIdx.x * 2 + r;
    if (row >= NN) return;
    const float* hr = h + (size_t)row * D;
    float acc = b[j];
#pragma unroll
    for (int k = 0; k < D; ++k)
        acc = fmaf(hr[k], Ws[k * DO + j], acc);
    out[(size_t)row * DO + j] = acc;
}

// ---------------------------------------------------------------------------
extern "C" void kernel_launch(void* const* d_in, const int* in_sizes, int n_in,
                              void* d_out, int out_size, void* d_ws, size_t ws_size,
                              hipStream_t stream) {
    const float* x     = (const float*)d_in[0];
    const void*  edges = d_in[1];
    const float* W     = (const float*)d_in[2];
    const float* b     = (const float*)d_in[3];
    float* out = (float*)d_out;

    char* ws = (char*)d_ws;
    const size_t SZ_H = (size_t)NN * D * sizeof(float);  // 25.6 MB
    float* hA  = (float*)ws;
    float* hB  = (float*)(ws + SZ_H);
    float* deg = (float*)(ws + 2 * SZ_H);                // also holds dinv in place
    int*   src = (int*)(ws + 2 * SZ_H + (size_t)NN * sizeof(float));
    int*   dst = src + NE;
    int*   flag = dst + NE;

    const dim3 B(256);
    const int GB = 2048;  // grid-stride blocks (max-occupancy resident threads)

    detect_i64<<<1, 256, 0, stream>>>((const uint32_t*)edges, flag);
    convert_edges<<<GB, B, 0, stream>>>(edges, flag, src, dst);

    // degree -> dinv (in place)
    zero_f4<<<128, B, 0, stream>>>((float4*)deg, NN / 4);
    deg_kernel<<<GB, B, 0, stream>>>(dst, deg);
    dinv_kernel<<<(NN + 255) / 256, B, 0, stream>>>(deg);

    // layer 0: agg into hA, combine with x in place
    zero_f4<<<GB, B, 0, stream>>>((float4*)hA, NN * 16);
    scatter<<<GB, B, 0, stream>>>((const float4*)x, src, dst, hA);
    combine0<<<GB, B, 0, stream>>>((const float4*)x, (float4*)hA, deg);

    // layers 1..3 (residual), ping-pong hA/hB
    float* cur = hA;
    float* nxt = hB;
    for (int l = 1; l < 4; ++l) {
        zero_f4<<<GB, B, 0, stream>>>((float4*)nxt, NN * 16);
        scatter<<<GB, B, 0, stream>>>((const float4*)cur, src, dst, nxt);
        combineR<<<GB, B, 0, stream>>>((const float4*)cur, (float4*)nxt, deg);
        float* t = cur; cur = nxt; nxt = t;
    }

    matmul_kernel<<<NN / 2, B, 0, stream>>>(cur, W, b, out);
}

// Round 2
// 647.715 us; speedup vs baseline: 8.8935x; 8.8935x over previous
//
#include <hip/hip_runtime.h>
#include <stdint.h>

constexpr int NN = 100000;   // nodes
constexpr int NE = 1600000;  // edges
constexpr int D  = 64;       // feature dim
constexpr int DO = 128;      // output dim
constexpr int NB = (NN + 255) / 256;  // scan blocks = 391

// ---------------------------------------------------------------------------
// Detect whether edge_index buffer is int64 or int32.
// int64 values are < 2^17, so every odd 32-bit word is 0.
__global__ void detect_i64(const uint32_t* __restrict__ e, int* __restrict__ flag) {
    __shared__ uint32_t acc;
    if (threadIdx.x == 0) acc = 0u;
    __syncthreads();
    uint32_t w = e[2 * threadIdx.x + 1];
    atomicOr(&acc, w);
    __syncthreads();
    if (threadIdx.x == 0) *flag = (acc == 0u) ? 1 : 0;
}

__global__ void zero_int(int* __restrict__ p, int n) {
    for (int i = blockIdx.x * blockDim.x + threadIdx.x; i < n;
         i += gridDim.x * blockDim.x)
        p[i] = 0;
}

// count in-degree (int atomics)
__global__ void count_dst(const void* __restrict__ e, const int* __restrict__ flag,
                          int* __restrict__ cnt) {
    const int f = *flag;
    for (int i = blockIdx.x * blockDim.x + threadIdx.x; i < NE;
         i += gridDim.x * blockDim.x) {
        int d = f ? (int)((const long long*)e)[NE + i] : ((const int*)e)[NE + i];
        atomicAdd(&cnt[d], 1);
    }
}

__global__ void dinv_kernel(const int* __restrict__ cnt, float* __restrict__ dinv) {
    int i = blockIdx.x * blockDim.x + threadIdx.x;
    if (i < NN) dinv[i] = 1.0f / fmaxf((float)cnt[i], 1.0f);
}

// ---------------------------------------------------------------------------
// 3-kernel exclusive scan of cnt -> rowptr[NN+1]
__global__ void scan_a(const int* __restrict__ cnt, int* __restrict__ rowptr,
                       int* __restrict__ bsum) {
    __shared__ int s[2][256];
    const int tid = threadIdx.x;
    const int i = blockIdx.x * 256 + tid;
    int v = (i < NN) ? cnt[i] : 0;
    int pb = 0;
    s[0][tid] = v;
    __syncthreads();
#pragma unroll
    for (int off = 1; off < 256; off <<= 1) {
        int t = s[pb][tid] + ((tid >= off) ? s[pb][tid - off] : 0);
        pb ^= 1;
        s[pb][tid] = t;
        __syncthreads();
    }
    int incl = s[pb][tid];
    if (i < NN) rowptr[i] = incl - v;  // exclusive
    if (tid == 255) bsum[blockIdx.x] = incl;
}

__global__ void scan_b(int* __restrict__ bsum, int* __restrict__ rowptr) {
    if (threadIdx.x == 0 && blockIdx.x == 0) {
        int running = 0;
        for (int b = 0; b < NB; ++b) {
            int t = bsum[b];
            bsum[b] = running;
            running += t;
        }
        rowptr[NN] = running;  // == NE
    }
}

__global__ void scan_c(int* __restrict__ rowptr, const int* __restrict__ bsum) {
    const int i = blockIdx.x * 256 + threadIdx.x;
    if (i < NN) rowptr[i] += bsum[blockIdx.x];
}

__global__ void copy_int(const int* __restrict__ a, int* __restrict__ b, int n) {
    for (int i = blockIdx.x * blockDim.x + threadIdx.x; i < n;
         i += gridDim.x * blockDim.x)
        b[i] = a[i];
}

// scatter edge source ids into CSR buckets (1.6M int atomics, order arbitrary)
__global__ void fill_csr(const void* __restrict__ e, const int* __restrict__ flag,
                         int* __restrict__ cursor, int* __restrict__ csr_src) {
    const int f = *flag;
    for (int i = blockIdx.x * blockDim.x + threadIdx.x; i < NE;
         i += gridDim.x * blockDim.x) {
        int s, d;
        if (f) {
            s = (int)((const long long*)e)[i];
            d = (int)((const long long*)e)[NE + i];
        } else {
            s = ((const int*)e)[i];
            d = ((const int*)e)[NE + i];
        }
        int p = atomicAdd(&cursor[d], 1);
        csr_src[p] = s;
    }
}

// ---------------------------------------------------------------------------
// Fused WL layer: one wave per node. 4 groups of 16 lanes pull 4 edges
// concurrently (16 x float4 = 256B coalesced row read per edge), shfl-reduce
// across groups, fused combine + write.
// MODE 0: out = relu(0.5*(h + agg*dinv))           (layer 0, h = x)
// MODE 1: out = h + relu(0.5*(h + agg*dinv))       (residual layers)
template <int MODE>
__global__ __launch_bounds__(256) void wl_layer(
    const float4* __restrict__ h4, const int* __restrict__ rowptr,
    const int* __restrict__ csr_src, const float* __restrict__ dinv,
    float4* __restrict__ out4) {
    const int node = (blockIdx.x * blockDim.x + threadIdx.x) >> 6;
    if (node >= NN) return;
    const int lane = threadIdx.x & 63;
    const int g = lane >> 4;   // edge group 0..3
    const int q = lane & 15;   // float4 chunk within row

    const int beg = rowptr[node];
    const int end = rowptr[node + 1];

    float4 acc = make_float4(0.f, 0.f, 0.f, 0.f);
    for (int e = beg + g; e < end; e += 4) {
        const int s = csr_src[e];
        const float4 v = h4[(size_t)s * 16 + q];
        acc.x += v.x; acc.y += v.y; acc.z += v.z; acc.w += v.w;
    }
    // reduce across the 4 groups (lanes differing in bits 4,5)
#pragma unroll
    for (int off = 16; off < 64; off <<= 1) {
        acc.x += __shfl_xor(acc.x, off, 64);
        acc.y += __shfl_xor(acc.y, off, 64);
        acc.z += __shfl_xor(acc.z, off, 64);
        acc.w += __shfl_xor(acc.w, off, 64);
    }
    if (g == 0) {
        const float di = dinv[node];
        const float4 h = h4[(size_t)node * 16 + q];
        float4 r;
        if (MODE == 0) {
            r.x = fmaxf(0.5f * (h.x + acc.x * di), 0.f);
            r.y = fmaxf(0.5f * (h.y + acc.y * di), 0.f);
            r.z = fmaxf(0.5f * (h.z + acc.z * di), 0.f);
            r.w = fmaxf(0.5f * (h.w + acc.w * di), 0.f);
        } else {
            r.x = h.x + fmaxf(0.5f * (h.x + acc.x * di), 0.f);
            r.y = h.y + fmaxf(0.5f * (h.y + acc.y * di), 0.f);
            r.z = h.z + fmaxf(0.5f * (h.z + acc.z * di), 0.f);
            r.w = h.w + fmaxf(0.5f * (h.w + acc.w * di), 0.f);
        }
        out4[(size_t)node * 16 + q] = r;
    }
}

// ---------------------------------------------------------------------------
// out[i][j] = dot(h[i,:], W[:,j]) + b[j].  W staged in LDS, 2 rows/block.
__global__ __launch_bounds__(256) void matmul_kernel(
    const float* __restrict__ h, const float* __restrict__ W,
    const float* __restrict__ b, float* __restrict__ out) {
    __shared__ float Ws[D * DO];  // 32 KB
    for (int i = threadIdx.x; i < D * DO; i += 256) Ws[i] = W[i];
    __syncthreads();
    const int j   = threadIdx.x & (DO - 1);
    const int r   = threadIdx.x >> 7;
    const int row = blockIdx.x * 2 + r;
    if (row >= NN) return;
    const float* hr = h + (size_t)row * D;
    float acc = b[j];
#pragma unroll
    for (int k = 0; k < D; ++k)
        acc = fmaf(hr[k], Ws[k * DO + j], acc);
    out[(size_t)row * DO + j] = acc;
}

// ---------------------------------------------------------------------------
extern "C" void kernel_launch(void* const* d_in, const int* in_sizes, int n_in,
                              void* d_out, int out_size, void* d_ws, size_t ws_size,
                              hipStream_t stream) {
    const float* x     = (const float*)d_in[0];
    const void*  edges = d_in[1];
    const float* W     = (const float*)d_in[2];
    const float* b     = (const float*)d_in[3];
    float* out = (float*)d_out;

    char* ws = (char*)d_ws;
    const size_t SZ_H = (size_t)NN * D * sizeof(float);  // 25,600,000
    float* hA     = (float*)ws;
    float* hB     = (float*)(ws + SZ_H);
    int*   csr    = (int*)(ws + 2 * SZ_H);                       // NE ints
    int*   rowptr = (int*)(ws + 2 * SZ_H + (size_t)NE * 4);      // NN+1 ints
    int*   cursor = rowptr + (NN + 16);                          // NN ints
    int*   cnt    = cursor + NN;                                 // NN ints
    float* dinv   = (float*)(cnt + NN);                          // NN floats
    int*   bsum   = (int*)(dinv + NN);                           // NB ints
    int*   flag   = bsum + NB + 1;

    const dim3 B(256);
    const int GB = 2048;

    detect_i64<<<1, 256, 0, stream>>>((const uint32_t*)edges, flag);

    // degree + dinv
    zero_int<<<128, B, 0, stream>>>(cnt, NN);
    count_dst<<<GB, B, 0, stream>>>(edges, flag, cnt);
    dinv_kernel<<<(NN + 255) / 256, B, 0, stream>>>(cnt, dinv);

    // CSR build: scan + fill
    scan_a<<<NB, B, 0, stream>>>(cnt, rowptr, bsum);
    scan_b<<<1, 64, 0, stream>>>(bsum, rowptr);
    scan_c<<<NB, B, 0, stream>>>(rowptr, bsum);
    copy_int<<<256, B, 0, stream>>>(rowptr, cursor, NN);
    fill_csr<<<GB, B, 0, stream>>>(edges, flag, cursor, csr);

    // fused WL layers (one wave per node), ping-pong hA/hB
    const int LG = (NN * 64 + 255) / 256;  // 25000 blocks
    wl_layer<0><<<LG, B, 0, stream>>>((const float4*)x,  rowptr, csr, dinv, (float4*)hA);
    wl_layer<1><<<LG, B, 0, stream>>>((const float4*)hA, rowptr, csr, dinv, (float4*)hB);
    wl_layer<1><<<LG, B, 0, stream>>>((const float4*)hB, rowptr, csr, dinv, (float4*)hA);
    wl_layer<1><<<LG, B, 0, stream>>>((const float4*)hA, rowptr, csr, dinv, (float4*)hB);

    matmul_kernel<<<NN / 2, B, 0, stream>>>(hB, W, b, out);
}

// Round 3
// 560.628 us; speedup vs baseline: 10.2750x; 1.1553x over previous
//
#include <hip/hip_runtime.h>
#include <stdint.h>

constexpr int NN = 100000;   // nodes
constexpr int NE = 1600000;  // edges
constexpr int D  = 64;       // feature dim
constexpr int DO = 128;      // output dim
constexpr int NB = (NN + 255) / 256;  // scan blocks = 391

// ---------------------------------------------------------------------------
// Detect whether edge_index buffer is int64 or int32.
__global__ void detect_i64(const uint32_t* __restrict__ e, int* __restrict__ flag) {
    __shared__ uint32_t acc;
    if (threadIdx.x == 0) acc = 0u;
    __syncthreads();
    uint32_t w = e[2 * threadIdx.x + 1];
    atomicOr(&acc, w);
    __syncthreads();
    if (threadIdx.x == 0) *flag = (acc == 0u) ? 1 : 0;
}

__global__ void zero_int(int* __restrict__ p, int n) {
    for (int i = blockIdx.x * blockDim.x + threadIdx.x; i < n;
         i += gridDim.x * blockDim.x)
        p[i] = 0;
}

__global__ void count_dst(const void* __restrict__ e, const int* __restrict__ flag,
                          int* __restrict__ cnt) {
    const int f = *flag;
    for (int i = blockIdx.x * blockDim.x + threadIdx.x; i < NE;
         i += gridDim.x * blockDim.x) {
        int d = f ? (int)((const long long*)e)[NE + i] : ((const int*)e)[NE + i];
        atomicAdd(&cnt[d], 1);
    }
}

__global__ void dinv_kernel(const int* __restrict__ cnt, float* __restrict__ dinv) {
    int i = blockIdx.x * blockDim.x + threadIdx.x;
    if (i < NN) dinv[i] = 1.0f / fmaxf((float)cnt[i], 1.0f);
}

// ---------------------------------------------------------------------------
// 3-kernel exclusive scan of cnt -> rowptr[NN+1]
__global__ void scan_a(const int* __restrict__ cnt, int* __restrict__ rowptr,
                       int* __restrict__ bsum) {
    __shared__ int s[2][256];
    const int tid = threadIdx.x;
    const int i = blockIdx.x * 256 + tid;
    int v = (i < NN) ? cnt[i] : 0;
    int pb = 0;
    s[0][tid] = v;
    __syncthreads();
#pragma unroll
    for (int off = 1; off < 256; off <<= 1) {
        int t = s[pb][tid] + ((tid >= off) ? s[pb][tid - off] : 0);
        pb ^= 1;
        s[pb][tid] = t;
        __syncthreads();
    }
    int incl = s[pb][tid];
    if (i < NN) rowptr[i] = incl - v;  // exclusive
    if (tid == 255) bsum[blockIdx.x] = incl;
}

__global__ void scan_b(int* __restrict__ bsum, int* __restrict__ rowptr) {
    if (threadIdx.x == 0 && blockIdx.x == 0) {
        int running = 0;
        for (int b = 0; b < NB; ++b) {
            int t = bsum[b];
            bsum[b] = running;
            running += t;
        }
        rowptr[NN] = running;  // == NE
    }
}

__global__ void scan_c(int* __restrict__ rowptr, const int* __restrict__ bsum) {
    const int i = blockIdx.x * 256 + threadIdx.x;
    if (i < NN) rowptr[i] += bsum[blockIdx.x];
}

__global__ void copy_int(const int* __restrict__ a, int* __restrict__ b, int n) {
    for (int i = blockIdx.x * blockDim.x + threadIdx.x; i < n;
         i += gridDim.x * blockDim.x)
        b[i] = a[i];
}

__global__ void fill_csr(const void* __restrict__ e, const int* __restrict__ flag,
                         int* __restrict__ cursor, int* __restrict__ csr_src) {
    const int f = *flag;
    for (int i = blockIdx.x * blockDim.x + threadIdx.x; i < NE;
         i += gridDim.x * blockDim.x) {
        int s, d;
        if (f) {
            s = (int)((const long long*)e)[i];
            d = (int)((const long long*)e)[NE + i];
        } else {
            s = ((const int*)e)[i];
            d = ((const int*)e)[NE + i];
        }
        int p = atomicAdd(&cursor[d], 1);
        csr_src[p] = s;
    }
}

// ---------------------------------------------------------------------------
// Fused WL layer: one wave per node, 4 groups of 16 lanes pull edges.
// 2-deep unroll: two 256B row-gathers in flight per group.
template <int MODE>
__global__ __launch_bounds__(256) void wl_layer(
    const float4* __restrict__ h4, const int* __restrict__ rowptr,
    const int* __restrict__ csr_src, const float* __restrict__ dinv,
    float4* __restrict__ out4) {
    const int node = (blockIdx.x * blockDim.x + threadIdx.x) >> 6;
    if (node >= NN) return;
    const int lane = threadIdx.x & 63;
    const int g = lane >> 4;   // edge group 0..3
    const int q = lane & 15;   // float4 chunk within row

    const int beg = rowptr[node];
    const int end = rowptr[node + 1];

    float4 a0 = make_float4(0.f, 0.f, 0.f, 0.f);
    float4 a1 = make_float4(0.f, 0.f, 0.f, 0.f);
    int e = beg + g;
    for (; e + 4 < end; e += 8) {
        const int s0 = csr_src[e];
        const int s1 = csr_src[e + 4];
        const float4 v0 = h4[(size_t)s0 * 16 + q];
        const float4 v1 = h4[(size_t)s1 * 16 + q];
        a0.x += v0.x; a0.y += v0.y; a0.z += v0.z; a0.w += v0.w;
        a1.x += v1.x; a1.y += v1.y; a1.z += v1.z; a1.w += v1.w;
    }
    if (e < end) {
        const float4 v = h4[(size_t)csr_src[e] * 16 + q];
        a0.x += v.x; a0.y += v.y; a0.z += v.z; a0.w += v.w;
    }
    float4 acc;
    acc.x = a0.x + a1.x; acc.y = a0.y + a1.y;
    acc.z = a0.z + a1.z; acc.w = a0.w + a1.w;

#pragma unroll
    for (int off = 16; off < 64; off <<= 1) {
        acc.x += __shfl_xor(acc.x, off, 64);
        acc.y += __shfl_xor(acc.y, off, 64);
        acc.z += __shfl_xor(acc.z, off, 64);
        acc.w += __shfl_xor(acc.w, off, 64);
    }
    if (g == 0) {
        const float di = dinv[node];
        const float4 h = h4[(size_t)node * 16 + q];
        float4 r;
        if (MODE == 0) {
            r.x = fmaxf(0.5f * (h.x + acc.x * di), 0.f);
            r.y = fmaxf(0.5f * (h.y + acc.y * di), 0.f);
            r.z = fmaxf(0.5f * (h.z + acc.z * di), 0.f);
            r.w = fmaxf(0.5f * (h.w + acc.w * di), 0.f);
        } else {
            r.x = h.x + fmaxf(0.5f * (h.x + acc.x * di), 0.f);
            r.y = h.y + fmaxf(0.5f * (h.y + acc.y * di), 0.f);
            r.z = h.z + fmaxf(0.5f * (h.z + acc.z * di), 0.f);
            r.w = h.w + fmaxf(0.5f * (h.w + acc.w * di), 0.f);
        }
        out4[(size_t)node * 16 + q] = r;
    }
}

// ---------------------------------------------------------------------------
// out = h @ W + b. Persistent blocks: W^T staged once per block into LDS
// ([128][68] floats, 17-float4 row stride -> conflict-free ds_read_b128).
// Thread = 1 col x 4 rows; chunk = 8 rows per block-iteration.
constexpr int WT_STRIDE = 68;             // floats; 17 float4s (odd -> no conflict)
constexpr int NCHUNK = NN / 8;            // 12500 exact

__global__ __launch_bounds__(256) void matmul_kernel(
    const float4* __restrict__ h4, const float* __restrict__ W,
    const float* __restrict__ b, float* __restrict__ out) {
    __shared__ __align__(16) float Wt[DO * WT_STRIDE];  // 34.8 KB
    const int tid = threadIdx.x;
    for (int i = tid; i < D * DO; i += 256) {
        const int k = i >> 7, j = i & 127;
        Wt[j * WT_STRIDE + k] = W[i];
    }
    __syncthreads();

    const int j = tid & 127;        // output column
    const int s = tid >> 7;         // row slot 0..1
    const float bj = b[j];
    const float4* wt4 = (const float4*)(Wt + j * WT_STRIDE);

    for (int chunk = blockIdx.x; chunk < NCHUNK; chunk += gridDim.x) {
        const int row0 = chunk * 8 + s * 4;
        const float4* hr0 = h4 + (size_t)(row0 + 0) * 16;
        const float4* hr1 = h4 + (size_t)(row0 + 1) * 16;
        const float4* hr2 = h4 + (size_t)(row0 + 2) * 16;
        const float4* hr3 = h4 + (size_t)(row0 + 3) * 16;
        float acc0 = bj, acc1 = bj, acc2 = bj, acc3 = bj;
#pragma unroll
        for (int k4 = 0; k4 < 16; ++k4) {
            const float4 w = wt4[k4];
            const float4 h0 = hr0[k4];
            const float4 h1 = hr1[k4];
            const float4 h2 = hr2[k4];
            const float4 h3 = hr3[k4];
            acc0 = fmaf(h0.x, w.x, acc0); acc0 = fmaf(h0.y, w.y, acc0);
            acc0 = fmaf(h0.z, w.z, acc0); acc0 = fmaf(h0.w, w.w, acc0);
            acc1 = fmaf(h1.x, w.x, acc1); acc1 = fmaf(h1.y, w.y, acc1);
            acc1 = fmaf(h1.z, w.z, acc1); acc1 = fmaf(h1.w, w.w, acc1);
            acc2 = fmaf(h2.x, w.x, acc2); acc2 = fmaf(h2.y, w.y, acc2);
            acc2 = fmaf(h2.z, w.z, acc2); acc2 = fmaf(h2.w, w.w, acc2);
            acc3 = fmaf(h3.x, w.x, acc3); acc3 = fmaf(h3.y, w.y, acc3);
            acc3 = fmaf(h3.z, w.z, acc3); acc3 = fmaf(h3.w, w.w, acc3);
        }
        float* o = out + (size_t)row0 * DO + j;
        o[0 * DO] = acc0;
        o[1 * DO] = acc1;
        o[2 * DO] = acc2;
        o[3 * DO] = acc3;
    }
}

// ---------------------------------------------------------------------------
extern "C" void kernel_launch(void* const* d_in, const int* in_sizes, int n_in,
                              void* d_out, int out_size, void* d_ws, size_t ws_size,
                              hipStream_t stream) {
    const float* x     = (const float*)d_in[0];
    const void*  edges = d_in[1];
    const float* W     = (const float*)d_in[2];
    const float* b     = (const float*)d_in[3];
    float* out = (float*)d_out;

    char* ws = (char*)d_ws;
    const size_t SZ_H = (size_t)NN * D * sizeof(float);  // 25,600,000
    float* hA     = (float*)ws;
    float* hB     = (float*)(ws + SZ_H);
    int*   csr    = (int*)(ws + 2 * SZ_H);                       // NE ints
    int*   rowptr = (int*)(ws + 2 * SZ_H + (size_t)NE * 4);      // NN+1 ints
    int*   cursor = rowptr + (NN + 16);                          // NN ints
    int*   cnt    = cursor + NN;                                 // NN ints
    float* dinv   = (float*)(cnt + NN);                          // NN floats
    int*   bsum   = (int*)(dinv + NN);                           // NB ints
    int*   flag   = bsum + NB + 1;

    const dim3 B(256);
    const int GB = 2048;

    detect_i64<<<1, 256, 0, stream>>>((const uint32_t*)edges, flag);

    zero_int<<<128, B, 0, stream>>>(cnt, NN);
    count_dst<<<GB, B, 0, stream>>>(edges, flag, cnt);
    dinv_kernel<<<(NN + 255) / 256, B, 0, stream>>>(cnt, dinv);

    scan_a<<<NB, B, 0, stream>>>(cnt, rowptr, bsum);
    scan_b<<<1, 64, 0, stream>>>(bsum, rowptr);
    scan_c<<<NB, B, 0, stream>>>(rowptr, bsum);
    copy_int<<<256, B, 0, stream>>>(rowptr, cursor, NN);
    fill_csr<<<GB, B, 0, stream>>>(edges, flag, cursor, csr);

    const int LG = (NN * 64 + 255) / 256;  // 25000 blocks
    wl_layer<0><<<LG, B, 0, stream>>>((const float4*)x,  rowptr, csr, dinv, (float4*)hA);
    wl_layer<1><<<LG, B, 0, stream>>>((const float4*)hA, rowptr, csr, dinv, (float4*)hB);
    wl_layer<1><<<LG, B, 0, stream>>>((const float4*)hB, rowptr, csr, dinv, (float4*)hA);
    wl_layer<1><<<LG, B, 0, stream>>>((const float4*)hA, rowptr, csr, dinv, (float4*)hB);

    matmul_kernel<<<1024, B, 0, stream>>>((const float4*)hB, W, b, out);
}

// Round 4
// 401.268 us; speedup vs baseline: 14.3556x; 1.3971x over previous
//
#include <hip/hip_runtime.h>
#include <stdint.h>

constexpr int NN = 100000;   // nodes
constexpr int NE = 1600000;  // edges
constexpr int D  = 64;       // feature dim
constexpr int DO = 128;      // output dim

constexpr int BSHIFT = 9;                       // 512 nodes per bucket
constexpr int BMASK  = (1 << BSHIFT) - 1;       // 511
constexpr int NBKT   = (NN + BMASK) / (1 << BSHIFT);  // 196
constexpr int CHUNK  = 4096;                    // edges per place/hist block
constexpr int NCHUNK_E = (NE + CHUNK - 1) / CHUNK;    // 391
constexpr int IMG_CAP = 16384;                  // max edges/bucket (mean 8192, sigma 90)

// ---------------------------------------------------------------------------
// Detect whether edge_index buffer is int64 or int32 (odd words all zero).
__global__ void detect_i64(const uint32_t* __restrict__ e, int* __restrict__ flag) {
    __shared__ uint32_t acc;
    if (threadIdx.x == 0) acc = 0u;
    __syncthreads();
    uint32_t w = e[2 * threadIdx.x + 1];
    atomicOr(&acc, w);
    __syncthreads();
    if (threadIdx.x == 0) *flag = (acc == 0u) ? 1 : 0;
}

__global__ void zero_int(int* __restrict__ p, int n) {
    int i = blockIdx.x * blockDim.x + threadIdx.x;
    if (i < n) p[i] = 0;
}

// ---------------------------------------------------------------------------
// Pass 1a: coarse histogram (196 buckets), LDS-aggregated.
__global__ __launch_bounds__(256) void hist_kernel(const void* __restrict__ e,
                                                   const int* __restrict__ flag,
                                                   int* __restrict__ bktcnt) {
    __shared__ int cnt[256];
    const int tid = threadIdx.x;
    cnt[tid] = 0;
    __syncthreads();
    const int f = *flag;
    const int base = blockIdx.x * CHUNK;
    const int lim = min(CHUNK, NE - base);
    for (int t = tid; t < lim; t += 256) {
        int d = f ? (int)((const long long*)e)[NE + base + t]
                  : ((const int*)e)[NE + base + t];
        atomicAdd(&cnt[d >> BSHIFT], 1);
    }
    __syncthreads();
    if (tid < NBKT && cnt[tid]) atomicAdd(&bktcnt[tid], cnt[tid]);
}

// Pass 1b: scan 196 bucket sizes -> gbase[NBKT+1], init gcursor.
__global__ void scan_bkt(const int* __restrict__ bktcnt, int* __restrict__ gbase,
                         int* __restrict__ gcursor) {
    __shared__ int s[256];
    __shared__ int o[257];
    const int tid = threadIdx.x;
    s[tid] = (tid < NBKT) ? bktcnt[tid] : 0;
    __syncthreads();
    if (tid == 0) {
        int run = 0;
        for (int bkt = 0; bkt < NBKT; ++bkt) { o[bkt] = run; run += s[bkt]; }
        o[NBKT] = run;
    }
    __syncthreads();
    if (tid < NBKT) { gbase[tid] = o[tid]; gcursor[tid] = o[tid]; }
    if (tid == 0) gbase[NBKT] = o[NBKT];
}

// Pass 2: bin 4096 edges into 196 buckets via LDS, flush coalesced runs.
// Packed word: (src << 9) | (dst & 511).  src < 2^17 -> fits 26 bits.
__global__ __launch_bounds__(256) void place_kernel(const void* __restrict__ e,
                                                    const int* __restrict__ flag,
                                                    int* __restrict__ gcursor,
                                                    uint32_t* __restrict__ bkt) {
    __shared__ int cnt[256];
    __shared__ int lbase[256];
    __shared__ int lcur[256];
    __shared__ int gb[256];
    __shared__ int sc[2][256];
    __shared__ uint32_t stage[CHUNK];   // 16 KB
    __shared__ uint8_t  sbkt[CHUNK];    // 4 KB
    const int tid = threadIdx.x;
    const int f = *flag;
    const int base = blockIdx.x * CHUNK;
    const int lim = min(CHUNK, NE - base);

    cnt[tid] = 0;
    __syncthreads();

    int      myb[16];
    uint32_t myp[16];
#pragma unroll
    for (int k = 0; k < 16; ++k) {
        const int t = tid + (k << 8);
        myb[k] = -1;
        if (t < lim) {
            int s, d;
            if (f) {
                s = (int)((const long long*)e)[base + t];
                d = (int)((const long long*)e)[NE + base + t];
            } else {
                s = ((const int*)e)[base + t];
                d = ((const int*)e)[NE + base + t];
            }
            const int bb = d >> BSHIFT;
            myb[k] = bb;
            myp[k] = ((uint32_t)s << BSHIFT) | (uint32_t)(d & BMASK);
            atomicAdd(&cnt[bb], 1);
        }
    }
    __syncthreads();

    // exclusive scan of cnt over 256 entries (Hillis-Steele)
    const int v = cnt[tid];
    int pb = 0;
    sc[0][tid] = v;
    __syncthreads();
#pragma unroll
    for (int off = 1; off < 256; off <<= 1) {
        int t = sc[pb][tid] + ((tid >= off) ? sc[pb][tid - off] : 0);
        pb ^= 1;
        sc[pb][tid] = t;
        __syncthreads();
    }
    lbase[tid] = sc[pb][tid] - v;   // exclusive
    lcur[tid]  = sc[pb][tid] - v;
    if (tid < NBKT && v > 0) gb[tid] = atomicAdd(&gcursor[tid], v);
    __syncthreads();

#pragma unroll
    for (int k = 0; k < 16; ++k) {
        if (myb[k] >= 0) {
            const int p = atomicAdd(&lcur[myb[k]], 1);
            stage[p] = myp[k];
            sbkt[p] = (uint8_t)myb[k];
        }
    }
    __syncthreads();

    for (int i = tid; i < lim; i += 256) {
        const int bb = sbkt[i];
        bkt[gb[bb] + (i - lbase[bb])] = stage[i];
    }
}

// Pass 3: one block per bucket. Exact-dst counting sort fully in LDS,
// coalesced CSR image copy-out + rowptr + dinv.
__global__ __launch_bounds__(512) void build_kernel(const uint32_t* __restrict__ bkt,
                                                    const int* __restrict__ gbase,
                                                    int* __restrict__ rowptr,
                                                    float* __restrict__ dinv,
                                                    int* __restrict__ csr) {
    __shared__ int cnt[512];
    __shared__ int sc[2][512];
    __shared__ uint32_t img[IMG_CAP];   // 64 KB
    const int tid = threadIdx.x;
    const int b = blockIdx.x;
    const int beg = gbase[b];
    const int end = gbase[b + 1];
    const int n = end - beg;
    const int node0 = b << BSHIFT;
    const int nnodes = min(512, NN - node0);

    cnt[tid] = 0;
    __syncthreads();
    for (int i = tid; i < n; i += 512) atomicAdd(&cnt[bkt[beg + i] & BMASK], 1);
    __syncthreads();

    const int deg = cnt[tid];
    int pb = 0;
    sc[0][tid] = deg;
    __syncthreads();
#pragma unroll
    for (int off = 1; off < 512; off <<= 1) {
        int t = sc[pb][tid] + ((tid >= off) ? sc[pb][tid - off] : 0);
        pb ^= 1;
        sc[pb][tid] = t;
        __syncthreads();
    }
    const int excl = sc[pb][tid] - deg;

    if (tid < nnodes) {
        rowptr[node0 + tid] = beg + excl;
        dinv[node0 + tid] = 1.0f / fmaxf((float)deg, 1.0f);
    }
    if (b == 0 && tid == 0) rowptr[NN] = NE;

    __syncthreads();
    cnt[tid] = excl;   // reuse as cursor
    __syncthreads();
    for (int i = tid; i < n; i += 512) {
        const uint32_t w = bkt[beg + i];
        const int p = atomicAdd(&cnt[w & BMASK], 1);
        img[p] = (int)(w >> BSHIFT);
    }
    __syncthreads();
    for (int i = tid; i < n; i += 512) csr[beg + i] = (int)img[i];
}

// ---------------------------------------------------------------------------
// Fused WL layer: one wave per node, 4 groups of 16 lanes, 4-deep unroll.
template <int MODE>
__global__ __launch_bounds__(256) void wl_layer(
    const float4* __restrict__ h4, const int* __restrict__ rowptr,
    const int* __restrict__ csr_src, const float* __restrict__ dinv,
    float4* __restrict__ out4) {
    const int node = (blockIdx.x * blockDim.x + threadIdx.x) >> 6;
    if (node >= NN) return;
    const int lane = threadIdx.x & 63;
    const int g = lane >> 4;   // edge group 0..3
    const int q = lane & 15;   // float4 chunk within row

    const int beg = rowptr[node];
    const int end = rowptr[node + 1];

    float4 a0 = make_float4(0.f, 0.f, 0.f, 0.f);
    float4 a1 = make_float4(0.f, 0.f, 0.f, 0.f);
    float4 a2 = make_float4(0.f, 0.f, 0.f, 0.f);
    float4 a3 = make_float4(0.f, 0.f, 0.f, 0.f);
    int e = beg + g;
    for (; e + 12 < end; e += 16) {
        const int s0 = csr_src[e];
        const int s1 = csr_src[e + 4];
        const int s2 = csr_src[e + 8];
        const int s3 = csr_src[e + 12];
        const float4 v0 = h4[(size_t)s0 * 16 + q];
        const float4 v1 = h4[(size_t)s1 * 16 + q];
        const float4 v2 = h4[(size_t)s2 * 16 + q];
        const float4 v3 = h4[(size_t)s3 * 16 + q];
        a0.x += v0.x; a0.y += v0.y; a0.z += v0.z; a0.w += v0.w;
        a1.x += v1.x; a1.y += v1.y; a1.z += v1.z; a1.w += v1.w;
        a2.x += v2.x; a2.y += v2.y; a2.z += v2.z; a2.w += v2.w;
        a3.x += v3.x; a3.y += v3.y; a3.z += v3.z; a3.w += v3.w;
    }
    for (; e < end; e += 4) {
        const float4 v = h4[(size_t)csr_src[e] * 16 + q];
        a0.x += v.x; a0.y += v.y; a0.z += v.z; a0.w += v.w;
    }
    float4 acc;
    acc.x = (a0.x + a1.x) + (a2.x + a3.x);
    acc.y = (a0.y + a1.y) + (a2.y + a3.y);
    acc.z = (a0.z + a1.z) + (a2.z + a3.z);
    acc.w = (a0.w + a1.w) + (a2.w + a3.w);

#pragma unroll
    for (int off = 16; off < 64; off <<= 1) {
        acc.x += __shfl_xor(acc.x, off, 64);
        acc.y += __shfl_xor(acc.y, off, 64);
        acc.z += __shfl_xor(acc.z, off, 64);
        acc.w += __shfl_xor(acc.w, off, 64);
    }
    if (g == 0) {
        const float di = dinv[node];
        const float4 h = h4[(size_t)node * 16 + q];
        float4 r;
        if (MODE == 0) {
            r.x = fmaxf(0.5f * (h.x + acc.x * di), 0.f);
            r.y = fmaxf(0.5f * (h.y + acc.y * di), 0.f);
            r.z = fmaxf(0.5f * (h.z + acc.z * di), 0.f);
            r.w = fmaxf(0.5f * (h.w + acc.w * di), 0.f);
        } else {
            r.x = h.x + fmaxf(0.5f * (h.x + acc.x * di), 0.f);
            r.y = h.y + fmaxf(0.5f * (h.y + acc.y * di), 0.f);
            r.z = h.z + fmaxf(0.5f * (h.z + acc.z * di), 0.f);
            r.w = h.w + fmaxf(0.5f * (h.w + acc.w * di), 0.f);
        }
        out4[(size_t)node * 16 + q] = r;
    }
}

// ---------------------------------------------------------------------------
// out = h @ W + b. Persistent blocks, W^T in LDS ([128][68], conflict-free).
constexpr int WT_STRIDE = 68;
constexpr int NCHUNK_M = NN / 8;

__global__ __launch_bounds__(256) void matmul_kernel(
    const float4* __restrict__ h4, const float* __restrict__ W,
    const float* __restrict__ b, float* __restrict__ out) {
    __shared__ __align__(16) float Wt[DO * WT_STRIDE];
    const int tid = threadIdx.x;
    for (int i = tid; i < D * DO; i += 256) {
        const int k = i >> 7, j = i & 127;
        Wt[j * WT_STRIDE + k] = W[i];
    }
    __syncthreads();

    const int j = tid & 127;
    const int s = tid >> 7;
    const float bj = b[j];
    const float4* wt4 = (const float4*)(Wt + j * WT_STRIDE);

    for (int chunk = blockIdx.x; chunk < NCHUNK_M; chunk += gridDim.x) {
        const int row0 = chunk * 8 + s * 4;
        const float4* hr0 = h4 + (size_t)(row0 + 0) * 16;
        const float4* hr1 = h4 + (size_t)(row0 + 1) * 16;
        const float4* hr2 = h4 + (size_t)(row0 + 2) * 16;
        const float4* hr3 = h4 + (size_t)(row0 + 3) * 16;
        float acc0 = bj, acc1 = bj, acc2 = bj, acc3 = bj;
#pragma unroll
        for (int k4 = 0; k4 < 16; ++k4) {
            const float4 w = wt4[k4];
            const float4 h0 = hr0[k4];
            const float4 h1 = hr1[k4];
            const float4 h2 = hr2[k4];
            const float4 h3 = hr3[k4];
            acc0 = fmaf(h0.x, w.x, acc0); acc0 = fmaf(h0.y, w.y, acc0);
            acc0 = fmaf(h0.z, w.z, acc0); acc0 = fmaf(h0.w, w.w, acc0);
            acc1 = fmaf(h1.x, w.x, acc1); acc1 = fmaf(h1.y, w.y, acc1);
            acc1 = fmaf(h1.z, w.z, acc1); acc1 = fmaf(h1.w, w.w, acc1);
            acc2 = fmaf(h2.x, w.x, acc2); acc2 = fmaf(h2.y, w.y, acc2);
            acc2 = fmaf(h2.z, w.z, acc2); acc2 = fmaf(h2.w, w.w, acc2);
            acc3 = fmaf(h3.x, w.x, acc3); acc3 = fmaf(h3.y, w.y, acc3);
            acc3 = fmaf(h3.z, w.z, acc3); acc3 = fmaf(h3.w, w.w, acc3);
        }
        float* o = out + (size_t)row0 * DO + j;
        o[0 * DO] = acc0;
        o[1 * DO] = acc1;
        o[2 * DO] = acc2;
        o[3 * DO] = acc3;
    }
}

// ---------------------------------------------------------------------------
extern "C" void kernel_launch(void* const* d_in, const int* in_sizes, int n_in,
                              void* d_out, int out_size, void* d_ws, size_t ws_size,
                              hipStream_t stream) {
    const float* x     = (const float*)d_in[0];
    const void*  edges = d_in[1];
    const float* W     = (const float*)d_in[2];
    const float* b     = (const float*)d_in[3];
    float* out = (float*)d_out;

    char* ws = (char*)d_ws;
    const size_t SZ_H = (size_t)NN * D * sizeof(float);  // 25,600,000
    float*    hA      = (float*)ws;
    float*    hB      = (float*)(ws + SZ_H);
    uint32_t* bkt     = (uint32_t*)(ws + 2 * SZ_H);                    // NE u32
    int*      csr     = (int*)(ws + 2 * SZ_H + (size_t)NE * 4);        // NE ints
    int*      rowptr  = (int*)(ws + 2 * SZ_H + (size_t)NE * 8);        // NN+1
    float*    dinv    = (float*)(rowptr + NN + 8);                     // NN
    int*      bktcnt  = (int*)(dinv + NN);                             // NBKT
    int*      gbase   = bktcnt + NBKT;                                 // NBKT+1
    int*      gcursor = gbase + NBKT + 1;                              // NBKT
    int*      flag    = gcursor + NBKT;

    const dim3 B(256);

    detect_i64<<<1, 256, 0, stream>>>((const uint32_t*)edges, flag);
    zero_int<<<1, 256, 0, stream>>>(bktcnt, NBKT);
    hist_kernel<<<NCHUNK_E, B, 0, stream>>>(edges, flag, bktcnt);
    scan_bkt<<<1, 256, 0, stream>>>(bktcnt, gbase, gcursor);
    place_kernel<<<NCHUNK_E, B, 0, stream>>>(edges, flag, gcursor, bkt);
    build_kernel<<<NBKT, 512, 0, stream>>>(bkt, gbase, rowptr, dinv, csr);

    const int LG = (NN * 64 + 255) / 256;  // 25000 blocks
    wl_layer<0><<<LG, B, 0, stream>>>((const float4*)x,  rowptr, csr, dinv, (float4*)hA);
    wl_layer<1><<<LG, B, 0, stream>>>((const float4*)hA, rowptr, csr, dinv, (float4*)hB);
    wl_layer<1><<<LG, B, 0, stream>>>((const float4*)hB, rowptr, csr, dinv, (float4*)hA);
    wl_layer<1><<<LG, B, 0, stream>>>((const float4*)hA, rowptr, csr, dinv, (float4*)hB);

    matmul_kernel<<<1024, B, 0, stream>>>((const float4*)hB, W, b, out);
}